// Round 4
// baseline (215.944 us; speedup 1.0000x reference)
//
#include <hip/hip_runtime.h>

typedef unsigned short u16;
typedef unsigned int   u32;

typedef short short8 __attribute__((ext_vector_type(8)));
typedef float floatx4 __attribute__((ext_vector_type(4)));
typedef int   i32x4  __attribute__((ext_vector_type(4)));   // native vec for nontemporal builtin

#define CDIM 128
#define K_NEG_LOG2E -1.4426950408889634f
#define CNT_SCALE 16777216.0   // 2^24: packs (sum, count) into one f64

// conc-binning: 32 bins x 32 concept rows; per-bin LDS slice = 32*512 B = 16 KB
#define NBINS 32
#define BIN_SHIFT 5
#define BIN_CAP 32768          // edges per bin region (mean 31250, +8.7 sigma)
#define LDS_CONC_BYTES 16384

__device__ __forceinline__ float bf2f_lo(u32 h) {
    union { u32 u; float f; } v; v.u = h << 16; return v.f;
}
__device__ __forceinline__ float bf2f_hi(u32 h) {
    union { u32 u; float f; } v; v.u = h & 0xffff0000u; return v.f;
}
__device__ __forceinline__ u16 f2bf(float f) {
    union { float f; u32 u; } v; v.f = f;
    u32 u = v.u;
    return (u16)((u + 0x7FFFu + ((u >> 16) & 1u)) >> 16);  // RNE
}
__device__ __forceinline__ float sig_std(float x) {
    return __builtin_amdgcn_rcpf(1.0f + __builtin_amdgcn_exp2f(x * K_NEG_LOG2E));
}

// One launch: zero f64 accumulators, convert weights to pre-scaled bf16,
// and SCATTER edge records into 32 conc-bin regions (byte-offset int4).
//   region b = idx4[b*BIN_CAP ...], count in cursor[b] (pre-zeroed by memset).
__global__ __launch_bounds__(256) void prep_kernel(
    const float* __restrict__ Wstu, const float* __restrict__ Witem,
    u32* __restrict__ Wbf_pair, float4* __restrict__ zero4, int nZero4,
    const int* __restrict__ stu_track, const int* __restrict__ item_index,
    const int* __restrict__ conc_index, const int* __restrict__ mean_index,
    int4* __restrict__ idx4, int* __restrict__ cursor, int E)
{
    const int tid = threadIdx.x;
    const int gtid = blockIdx.x * blockDim.x + tid;
    const int stride = gridDim.x * blockDim.x;
    for (int i = gtid; i < 16384; i += stride) {
        const float* W = (i & 8192) ? (Witem - 16384) : Wstu;
        const int j = i * 2;
        u32 lo = f2bf(W[j]     * K_NEG_LOG2E);
        u32 hi = f2bf(W[j + 1] * K_NEG_LOG2E);
        Wbf_pair[i] = lo | (hi << 16);
    }
    const float4 z = {0.f, 0.f, 0.f, 0.f};
    for (int i = gtid; i < nZero4; i += stride) zero4[i] = z;

    // ---- binned scatter (per-block hist -> one cursor reservation per bin) ----
    __shared__ int lhist[NBINS], lbase[NBINS], lcur[NBINS];
    const int CH = (E + gridDim.x - 1) / gridDim.x;
    const int e0 = blockIdx.x * CH;
    const int e1 = min(E, e0 + CH);
    if (tid < NBINS) lhist[tid] = 0;
    __syncthreads();
    for (int e = e0 + tid; e < e1; e += 256)
        atomicAdd(&lhist[conc_index[e] >> BIN_SHIFT], 1);
    __syncthreads();
    if (tid < NBINS) {
        lbase[tid] = atomicAdd(&cursor[tid], lhist[tid]);
        lcur[tid]  = 0;
    }
    __syncthreads();
    for (int e = e0 + tid; e < e1; e += 256) {
        const int c = conc_index[e];
        const int b = c >> BIN_SHIFT;
        const int p = lbase[b] + atomicAdd(&lcur[b], 1);
        if (p < BIN_CAP) {                       // ~9-sigma overflow guard
            int4 t;
            t.x = stu_track[e]  << 8;            // 256 B rows
            t.y = item_index[e] << 8;            // 256 B rows
            t.z = (c - (b << BIN_SHIFT)) << 9;   // LOCAL conc row * 512 B
            t.w = mean_index[e] << 3;            // f64 slots
            idx4[(b << 15) + p] = t;             // BIN_CAP == 1<<15
        }
    }
}

// One wave computes a 32-row tile; stores exp2(proj + bias) in bf16.
__device__ __forceinline__ void proj_tile32(
    const float* __restrict__ X, const u16* __restrict__ Wbf,
    const float* __restrict__ bias, u16* __restrict__ out,
    int nrows, int ostride, int ooff, int row0, int lane)
{
    const int m = lane & 15;   // A-row / B-col / D-col
    const int g = lane >> 4;   // k-quad

    short8 a[2][4];
#pragma unroll
    for (int t = 0; t < 2; ++t) {
        int arow = row0 + t * 16 + m;
        if (arow >= nrows) arow = nrows - 1;   // clamp; stores masked below
        const float* xrow = X + (size_t)arow * CDIM;
#pragma unroll
        for (int s = 0; s < 4; ++s) {
            float4 f0 = *(const float4*)(xrow + s * 32 + g * 8);
            float4 f1 = *(const float4*)(xrow + s * 32 + g * 8 + 4);
            a[t][s][0] = (short)f2bf(f0.x); a[t][s][1] = (short)f2bf(f0.y);
            a[t][s][2] = (short)f2bf(f0.z); a[t][s][3] = (short)f2bf(f0.w);
            a[t][s][4] = (short)f2bf(f1.x); a[t][s][5] = (short)f2bf(f1.y);
            a[t][s][6] = (short)f2bf(f1.z); a[t][s][7] = (short)f2bf(f1.w);
        }
    }

#pragma unroll
    for (int ct = 0; ct < 8; ++ct) {
        const u16* wrow = Wbf + (size_t)(ct * 16 + m) * CDIM;
        floatx4 acc0 = {0.f, 0.f, 0.f, 0.f};
        floatx4 acc1 = {0.f, 0.f, 0.f, 0.f};
#pragma unroll
        for (int s = 0; s < 4; ++s) {
            short8 b = *(const short8*)(wrow + s * 32 + g * 8);
            acc0 = __builtin_amdgcn_mfma_f32_16x16x32_bf16(a[0][s], b, acc0, 0, 0, 0);
            acc1 = __builtin_amdgcn_mfma_f32_16x16x32_bf16(a[1][s], b, acc1, 0, 0, 0);
        }
        const int col = ct * 16 + m;           // D: col = lane&15
        const float badd = bias ? bias[col] * K_NEG_LOG2E : 0.f;
#pragma unroll
        for (int i = 0; i < 4; ++i) {
            int r0 = row0 + g * 4 + i;         // D: row = (lane>>4)*4 + reg
            if (r0 < nrows)
                out[(size_t)r0 * ostride + ooff + col] =
                    f2bf(__builtin_amdgcn_exp2f(acc0[i] + badd));
            int r1 = r0 + 16;
            if (r1 < nrows)
                out[(size_t)r1 * ostride + ooff + col] =
                    f2bf(__builtin_amdgcn_exp2f(acc1[i] + badd));
        }
    }
}

// All four projections in one launch; wave-uniform segment select.
__global__ __launch_bounds__(256) void proj4_kernel(
    const float* __restrict__ stu_x, const float* __restrict__ item_x,
    const float* __restrict__ conc_x,
    const u16* __restrict__ Wstu_bf, const u16* __restrict__ Witem_bf,
    const float* __restrict__ b_stu, const float* __restrict__ b_item,
    u16* __restrict__ stu_p, u16* __restrict__ item_p, u16* __restrict__ conc_cat,
    int NS, int NI, int NC)
{
    const int lane = threadIdx.x & 63;
    int w = blockIdx.x * 4 + (threadIdx.x >> 6);
    const int T0 = (NS + 31) / 32, T1 = (NI + 31) / 32, T2 = (NC + 31) / 32;

    if (w < T0) { proj_tile32(stu_x, Wstu_bf, nullptr, stu_p, NS, 128, 0, w * 32, lane); return; }
    w -= T0;
    if (w < T1) { proj_tile32(item_x, Witem_bf, nullptr, item_p, NI, 128, 0, w * 32, lane); return; }
    w -= T1;
    if (w < T2) { proj_tile32(conc_x, Wstu_bf, b_stu, conc_cat, NC, 256, 0, w * 32, lane); return; }
    w -= T2;
    if (w < T2) { proj_tile32(conc_x, Witem_bf, b_item, conc_cat, NC, 256, 128, w * 32, lane); return; }
}

// 16 lanes per edge, 4 edges per wave. Tables hold E = 2^(pre-scaled proj).
// Each block serves ONE conc bin: its 16 KB conc slice lives in XOR-swizzled
// LDS, removing 512 of the 1040 L2-bytes/edge. stu/item stay global with the
// proven depth-1 data / depth-2 idx ping-pong pipeline (Round-0 structure).
__global__ __launch_bounds__(256) void edge_kernel(
    const u16* __restrict__ stu_p, const u16* __restrict__ item_p,
    const u16* __restrict__ conc_cat,
    const int4* __restrict__ idx4,     // binned records {stu,item,concLOCAL,mean}
    const int* __restrict__ cursor,    // per-bin edge counts
    const float* __restrict__ w_pred,
    double* __restrict__ sc, int NC)
{
    __shared__ u16 clds[LDS_CONC_BYTES / 2];
    const int bin = blockIdx.x & (NBINS - 1);

    // stage this bin's conc rows into LDS, XOR-swizzled to break the
    // 512B-row -> same-bank pattern: byte ^= ((byte>>9)&7)<<4
    {
        const int rows = min(32, NC - bin * 32);
        const int bytes = rows > 0 ? rows * 512 : 0;
        const char* src = (const char*)conc_cat + (size_t)bin * LDS_CONC_BYTES;
        for (int o = threadIdx.x * 16; o < bytes; o += 256 * 16) {
            uint4 v = *(const uint4*)(src + o);
            *(uint4*)((char*)clds + (o ^ (((o >> 9) & 7) << 4))) = v;
        }
    }
    __syncthreads();

    const int lane = threadIdx.x & 63;
    const int sub  = lane & 15;      // position within edge
    const int g    = lane >> 4;      // edge within quad

    const float4 wA = ((const float4*)w_pred)[sub * 2];
    const float4 wB = ((const float4*)w_pred)[sub * 2 + 1];
    float2 w2[4];
    w2[0] = make_float2(wA.x, wA.y); w2[1] = make_float2(wA.z, wA.w);
    w2[2] = make_float2(wB.x, wB.y); w2[3] = make_float2(wB.z, wB.w);
    const u32 lane_off = (u32)sub * 16;

    const int cnt = min(cursor[bin], BIN_CAP);
    if (cnt == 0) return;
    const int eBase = bin << 15;           // bin*BIN_CAP
    const int eEnd  = eBase + cnt;
    const int q0    = eBase >> 2;
    const int qEnd  = (eEnd + 3) >> 2;
    // wave index within this bin; stride = waves-per-bin
    const int wv = (blockIdx.x >> BIN_SHIFT) * (blockDim.x >> 6) + (threadIdx.x >> 6);
    const int SB = (int)((gridDim.x / NBINS) * (blockDim.x >> 6));
    int q = q0 + wv;
    if (q >= qEnd) return;

    const i32x4* __restrict__ idxv = (const i32x4*)idx4;

    // always-safe index load: clamped to last valid entry of this bin; NT
    auto ldidx = [&](int qq) -> i32x4 {
        int e = qq * 4 + g;
        e = (e < eEnd) ? e : (eEnd - 1);
        return __builtin_nontemporal_load(&idxv[e]);
    };
    auto compute = [&](const uint4& sv, const uint4& iv,
                       const uint4& ca, const uint4& cb,
                       u32 mw, int qq) {
        const u32 su[4] = {sv.x, sv.y, sv.z, sv.w};
        const u32 iu[4] = {iv.x, iv.y, iv.z, iv.w};
        const u32 au[4] = {ca.x, ca.y, ca.z, ca.w};
        const u32 bu[4] = {cb.x, cb.y, cb.z, cb.w};
        const float2 one = make_float2(1.f, 1.f);
        float2 vacc = make_float2(0.f, 0.f);
#pragma unroll
        for (int j = 0; j < 4; ++j) {
            float2 A  = make_float2(bf2f_lo(au[j]), bf2f_hi(au[j]));
            float2 Sx = make_float2(bf2f_lo(su[j]), bf2f_hi(su[j]));
            float2 B  = make_float2(bf2f_lo(bu[j]), bf2f_hi(bu[j]));
            float2 Ix = make_float2(bf2f_lo(iu[j]), bf2f_hi(iu[j]));
            float2 ea = A * Sx;                    // v_pk_mul_f32
            float2 eb = B * Ix;
            float2 den = (ea + one) * (eb + one);  // (1+ea)(1+eb)
            float2 num = eb - ea;
            float2 rd = make_float2(__builtin_amdgcn_rcpf(den.x),
                                    __builtin_amdgcn_rcpf(den.y));
            vacc += (num * rd) * w2[j];
        }
        float v = vacc.x + vacc.y;
        v += __shfl_xor(v, 1, 64);
        v += __shfl_xor(v, 2, 64);
        v += __shfl_xor(v, 4, 64);
        v += __shfl_xor(v, 8, 64);
        if (sub == 0 && (qq * 4 + g) < eEnd)
            atomicAdd((double*)((char*)sc + mw), (double)v + CNT_SCALE);
    };

#define GATH_S(I_, sv_, iv_) { \
        sv_ = *(const uint4*)((const char*)stu_p  + ((u32)(I_).x + lane_off)); \
        iv_ = *(const uint4*)((const char*)item_p + ((u32)(I_).y + lane_off)); }
#define LDSC(I_, ca_, cb_) { \
        u32 a_  = (u32)(I_).z + lane_off; \
        u32 as_ = a_ ^ (((a_ >> 9) & 7u) << 4); \
        ca_ = *(const uint4*)((const char*)clds + as_); \
        cb_ = *(const uint4*)((const char*)clds + as_ + 256); }

    // prefetch: issue NEXT stage's gathers + idx two ahead, fence, compute CURRENT
#define STEP(DA, DB, IA, IB, IC) { \
        GATH_S(I##IB, sv##DB, iv##DB); \
        LDSC(I##IB, ca##DB, cb##DB); \
        I##IC = ldidx(q + 2 * SB); \
        __builtin_amdgcn_sched_barrier(0); \
        compute(sv##DA, iv##DA, ca##DA, cb##DA, (u32)I##IA.w, q); \
        q += SB; \
        if (q >= qEnd) break; }

    // preamble
    i32x4 I0 = ldidx(q), I1 = ldidx(q + SB), I2, I3;
    uint4 sv0, iv0, ca0, cb0, sv1, iv1, ca1, cb1;
    GATH_S(I0, sv0, iv0);
    LDSC(I0, ca0, cb0);

    for (;;) {
        STEP(0, 1, 0, 1, 2)   // compute D0/I0, gather I1->D1, load I2
        STEP(1, 0, 1, 2, 3)   // compute D1/I1, gather I2->D0, load I3
        STEP(0, 1, 2, 3, 0)   // compute D0/I2, gather I3->D1, load I0
        STEP(1, 0, 3, 0, 1)   // compute D1/I3, gather I0->D0, load I1
    }
#undef STEP
#undef GATH_S
#undef LDSC
}

__global__ __launch_bounds__(256) void final_kernel(
    const double* __restrict__ sc,
    const float* __restrict__ b_pred, float* __restrict__ out, int M)
{
    const int i = blockIdx.x * blockDim.x + threadIdx.x;
    if (i < M) {
        const double acc = sc[i];
        const double cnt = rint(acc * (1.0 / CNT_SCALE));   // |sum| << 2^23
        const double sum = acc - cnt * CNT_SCALE;
        const float mean = (float)(sum / fmax(cnt, 1.0));
        out[i] = sig_std(mean + b_pred[0]);
    }
}

extern "C" void kernel_launch(void* const* d_in, const int* in_sizes, int n_in,
                              void* d_out, int out_size, void* d_ws, size_t ws_size,
                              hipStream_t stream) {
    const float* stu_x    = (const float*)d_in[0];
    const float* item_x   = (const float*)d_in[1];
    const float* conc_x   = (const float*)d_in[2];
    const float* W_stu    = (const float*)d_in[3];
    const float* b_stu    = (const float*)d_in[4];
    const float* W_item   = (const float*)d_in[5];
    const float* b_item   = (const float*)d_in[6];
    const float* W_pred   = (const float*)d_in[7];
    const float* b_pred   = (const float*)d_in[8];
    const int* stu_track  = (const int*)d_in[9];
    const int* item_index = (const int*)d_in[10];
    const int* conc_index = (const int*)d_in[11];
    const int* mean_index = (const int*)d_in[12];

    const int NS = in_sizes[0] / CDIM;
    const int NI = in_sizes[1] / CDIM;
    const int NC = in_sizes[2] / CDIM;
    const int E  = in_sizes[9];
    const int M  = out_size;

    // workspace layout (all pieces 16B-aligned)
    double* sc     = (double*)d_ws;              // [M] packed (sum + cnt*2^24)
    u16* Wstu_bf   = (u16*)(sc + M);             // Wstu_bf || Witem_bf contiguous
    u16* Witem_bf  = Wstu_bf + CDIM * CDIM;
    u16* stu_p     = Witem_bf + CDIM * CDIM;
    u16* item_p    = stu_p  + (size_t)NS * CDIM;
    u16* conc_cat  = item_p + (size_t)NI * CDIM; // [NC][256]: exp2 stu | item side
    int4* idx4     = (int4*)(conc_cat + (size_t)NC * 256);  // NBINS*BIN_CAP records
    int*  cursor   = (int*)(idx4 + (size_t)NBINS * BIN_CAP);

    hipMemsetAsync(cursor, 0, NBINS * sizeof(int), stream);

    const int nZero4 = (int)(((size_t)M * sizeof(double)) / 16);
    prep_kernel<<<1024, 256, 0, stream>>>(W_stu, W_item, (u32*)Wstu_bf,
                                          (float4*)sc, nZero4,
                                          stu_track, item_index, conc_index,
                                          mean_index, idx4, cursor, E);

    const int T0 = (NS + 31) / 32, T1 = (NI + 31) / 32, T2 = (NC + 31) / 32;
    const int totalWaves = T0 + T1 + 2 * T2;
    proj4_kernel<<<(totalWaves + 3) / 4, 256, 0, stream>>>(
        stu_x, item_x, conc_x, Wstu_bf, Witem_bf, b_stu, b_item,
        stu_p, item_p, conc_cat, NS, NI, NC);

    // 4096 blocks (proven grid): 128 blocks per bin, LDS 16KB -> 8 blocks/CU
    edge_kernel<<<4096, 256, 0, stream>>>(stu_p, item_p, conc_cat,
                                          idx4, cursor, W_pred, sc, NC);

    final_kernel<<<(M + 255) / 256, 256, 0, stream>>>(sc, b_pred, (float*)d_out, M);
}

// Round 6
// 201.190 us; speedup vs baseline: 1.0733x; 1.0733x over previous
//
#include <hip/hip_runtime.h>

typedef unsigned short u16;
typedef unsigned int   u32;

typedef short short8 __attribute__((ext_vector_type(8)));
typedef float floatx4 __attribute__((ext_vector_type(4)));

#define CDIM 128
#define K_NEG_LOG2E -1.4426950408889634f
#define CNT_SCALE 16777216.0   // 2^24: packs (sum, count) into one f64

__device__ __forceinline__ float bf2f_lo(u32 h) {
    union { u32 u; float f; } v; v.u = h << 16; return v.f;
}
__device__ __forceinline__ float bf2f_hi(u32 h) {
    union { u32 u; float f; } v; v.u = h & 0xffff0000u; return v.f;
}
__device__ __forceinline__ u16 f2bf(float f) {
    union { float f; u32 u; } v; v.f = f;
    u32 u = v.u;
    return (u16)((u + 0x7FFFu + ((u >> 16) & 1u)) >> 16);  // RNE
}
__device__ __forceinline__ float sig_std(float x) {
    return __builtin_amdgcn_rcpf(1.0f + __builtin_amdgcn_exp2f(x * K_NEG_LOG2E));
}

// VALU-only 16-lane row reduction via DPP row_shr adds (no ds_swizzle, no
// lgkm waits). After shr 1,2,4,8 the row total is in lane 15 of each
// 16-lane row (partial sums elsewhere). DPP rows on CDNA = 16 lanes.
__device__ __forceinline__ float rowsum16(float v) {
    int x;
    x = __builtin_amdgcn_update_dpp(0, __float_as_int(v), 0x111, 0xF, 0xF, true);
    v += __int_as_float(x);   // += lane-1
    x = __builtin_amdgcn_update_dpp(0, __float_as_int(v), 0x112, 0xF, 0xF, true);
    v += __int_as_float(x);   // += lane-2
    x = __builtin_amdgcn_update_dpp(0, __float_as_int(v), 0x114, 0xF, 0xF, true);
    v += __int_as_float(x);   // += lane-4
    x = __builtin_amdgcn_update_dpp(0, __float_as_int(v), 0x118, 0xF, 0xF, true);
    v += __int_as_float(x);   // += lane-8  -> lane15 = row total
    return v;
}

// One launch: zero f64 accumulators, convert weights to pre-scaled bf16,
// and pack the four edge-index arrays into one int4 of BYTE OFFSETS.
__global__ __launch_bounds__(256) void prep_kernel(
    const float* __restrict__ Wstu, const float* __restrict__ Witem,
    u32* __restrict__ Wbf_pair, float4* __restrict__ zero4, int nZero4,
    const int* __restrict__ stu_track, const int* __restrict__ item_index,
    const int* __restrict__ conc_index, const int* __restrict__ mean_index,
    int4* __restrict__ idx4, int E)
{
    const int tid = blockIdx.x * blockDim.x + threadIdx.x;
    const int stride = gridDim.x * blockDim.x;
    for (int i = tid; i < 16384; i += stride) {
        const float* W = (i & 8192) ? (Witem - 16384) : Wstu;
        const int j = i * 2;
        u32 lo = f2bf(W[j]     * K_NEG_LOG2E);
        u32 hi = f2bf(W[j + 1] * K_NEG_LOG2E);
        Wbf_pair[i] = lo | (hi << 16);
    }
    const float4 z = {0.f, 0.f, 0.f, 0.f};
    for (int i = tid; i < nZero4; i += stride) zero4[i] = z;
    for (int e = tid; e < E; e += stride) {
        int4 t;
        t.x = stu_track[e]  << 8;   // 256 B rows
        t.y = item_index[e] << 8;   // 256 B rows
        t.z = conc_index[e] << 9;   // 512 B rows (cat)
        t.w = mean_index[e] << 3;   // f64 slots
        idx4[e] = t;
    }
}

// One wave computes a 16-row tile; stores exp2(proj + bias) in bf16.
// (16-row tiles double the wave count vs 32-row: proj4 is HBM-bound at
//  ~2 blocks/CU with 32-row tiles; more waves = more BW in flight.)
__device__ __forceinline__ void proj_tile16(
    const float* __restrict__ X, const u16* __restrict__ Wbf,
    const float* __restrict__ bias, u16* __restrict__ out,
    int nrows, int ostride, int ooff, int row0, int lane)
{
    const int m = lane & 15;   // A-row / B-col / D-col
    const int g = lane >> 4;   // k-quad

    short8 a[4];
    {
        int arow = row0 + m;
        if (arow >= nrows) arow = nrows - 1;   // clamp; stores masked below
        const float* xrow = X + (size_t)arow * CDIM;
#pragma unroll
        for (int s = 0; s < 4; ++s) {
            float4 f0 = *(const float4*)(xrow + s * 32 + g * 8);
            float4 f1 = *(const float4*)(xrow + s * 32 + g * 8 + 4);
            a[s][0] = (short)f2bf(f0.x); a[s][1] = (short)f2bf(f0.y);
            a[s][2] = (short)f2bf(f0.z); a[s][3] = (short)f2bf(f0.w);
            a[s][4] = (short)f2bf(f1.x); a[s][5] = (short)f2bf(f1.y);
            a[s][6] = (short)f2bf(f1.z); a[s][7] = (short)f2bf(f1.w);
        }
    }

#pragma unroll
    for (int ct = 0; ct < 8; ++ct) {
        const u16* wrow = Wbf + (size_t)(ct * 16 + m) * CDIM;
        floatx4 acc = {0.f, 0.f, 0.f, 0.f};
#pragma unroll
        for (int s = 0; s < 4; ++s) {
            short8 b = *(const short8*)(wrow + s * 32 + g * 8);
            acc = __builtin_amdgcn_mfma_f32_16x16x32_bf16(a[s], b, acc, 0, 0, 0);
        }
        const int col = ct * 16 + m;           // D: col = lane&15
        const float badd = bias ? bias[col] * K_NEG_LOG2E : 0.f;
#pragma unroll
        for (int i = 0; i < 4; ++i) {
            int r = row0 + g * 4 + i;          // D: row = (lane>>4)*4 + reg
            if (r < nrows)
                out[(size_t)r * ostride + ooff + col] =
                    f2bf(__builtin_amdgcn_exp2f(acc[i] + badd));
        }
    }
}

// All four projections in one launch; wave-uniform segment select.
__global__ __launch_bounds__(256) void proj4_kernel(
    const float* __restrict__ stu_x, const float* __restrict__ item_x,
    const float* __restrict__ conc_x,
    const u16* __restrict__ Wstu_bf, const u16* __restrict__ Witem_bf,
    const float* __restrict__ b_stu, const float* __restrict__ b_item,
    u16* __restrict__ stu_p, u16* __restrict__ item_p, u16* __restrict__ conc_cat,
    int NS, int NI, int NC)
{
    const int lane = threadIdx.x & 63;
    int w = blockIdx.x * 4 + (threadIdx.x >> 6);
    const int T0 = (NS + 15) / 16, T1 = (NI + 15) / 16, T2 = (NC + 15) / 16;

    if (w < T0) { proj_tile16(stu_x, Wstu_bf, nullptr, stu_p, NS, 128, 0, w * 16, lane); return; }
    w -= T0;
    if (w < T1) { proj_tile16(item_x, Witem_bf, nullptr, item_p, NI, 128, 0, w * 16, lane); return; }
    w -= T1;
    if (w < T2) { proj_tile16(conc_x, Wstu_bf, b_stu, conc_cat, NC, 256, 0, w * 16, lane); return; }
    w -= T2;
    if (w < T2) { proj_tile16(conc_x, Witem_bf, b_item, conc_cat, NC, 256, 128, w * 16, lane); return; }
}

// 16 lanes per edge, 4 edges per wave. Tables hold E = 2^(pre-scaled proj).
// Proven round-0 structure (depth-1 data / depth-2 idx ping-pong, 4096
// blocks). This round's change: DPP row-reduction (VALU-only, removes the
// 4x serial ds_swizzle latency chain) + fma-form denominator.
__global__ __launch_bounds__(256) void edge_kernel(
    const u16* __restrict__ stu_p, const u16* __restrict__ item_p,
    const u16* __restrict__ conc_cat,
    const int4* __restrict__ idx4,     // byte offsets {stu, item, conc, mean}
    const float* __restrict__ w_pred,
    double* __restrict__ sc, int E)
{
    const int lane = threadIdx.x & 63;
    const int sub  = lane & 15;      // position within edge
    const int g    = lane >> 4;      // edge within quad
    const int waveId = (int)((blockIdx.x * blockDim.x + threadIdx.x) >> 6);
    const int S      = (int)((gridDim.x * blockDim.x) >> 6);   // wave stride

    const float4 wA = ((const float4*)w_pred)[sub * 2];
    const float4 wB = ((const float4*)w_pred)[sub * 2 + 1];
    float2 w2[4];
    w2[0] = make_float2(wA.x, wA.y); w2[1] = make_float2(wA.z, wA.w);
    w2[2] = make_float2(wB.x, wB.y); w2[3] = make_float2(wB.z, wB.w);
    const u32 lane_off = (u32)sub * 16;

    const int nQuads = (E + 3) >> 2;
    int q = waveId;
    if (q >= nQuads) return;

    // always-safe index load: edge id clamped to E-1
    auto ldidx = [&](int qq) -> int4 {
        int e = qq * 4 + g;
        e = (e < E) ? e : (E - 1);
        return idx4[e];
    };
    auto compute = [&](const uint4& sv, const uint4& iv,
                       const uint4& ca, const uint4& cb,
                       const int4& I, int qq) {
        const u32 su[4] = {sv.x, sv.y, sv.z, sv.w};
        const u32 iu[4] = {iv.x, iv.y, iv.z, iv.w};
        const u32 au[4] = {ca.x, ca.y, ca.z, ca.w};
        const u32 bu[4] = {cb.x, cb.y, cb.z, cb.w};
        float2 vacc = make_float2(0.f, 0.f);
#pragma unroll
        for (int j = 0; j < 4; ++j) {
            float2 A  = make_float2(bf2f_lo(au[j]), bf2f_hi(au[j]));
            float2 Sx = make_float2(bf2f_lo(su[j]), bf2f_hi(su[j]));
            float2 B  = make_float2(bf2f_lo(bu[j]), bf2f_hi(bu[j]));
            float2 Ix = make_float2(bf2f_lo(iu[j]), bf2f_hi(iu[j]));
            float2 ea = A * Sx;                    // v_pk_mul_f32
            float2 eb = B * Ix;
            float2 u  = make_float2(eb.x + 1.f, eb.y + 1.f);
            float2 den = make_float2(fmaf(ea.x, u.x, u.x),   // (1+ea)(1+eb)
                                     fmaf(ea.y, u.y, u.y));
            float2 num = eb - ea;
            float2 rd = make_float2(__builtin_amdgcn_rcpf(den.x),
                                    __builtin_amdgcn_rcpf(den.y));
            float2 t  = make_float2(num.x * rd.x, num.y * rd.y);
            vacc.x = fmaf(t.x, w2[j].x, vacc.x);
            vacc.y = fmaf(t.y, w2[j].y, vacc.y);
        }
        float v = rowsum16(vacc.x + vacc.y);       // total in sub==15
        if (sub == 15 && (qq * 4 + g) < E)
            atomicAdd((double*)((char*)sc + (u32)I.w), (double)v + CNT_SCALE);
    };

#define GATH(I_, sv_, iv_, ca_, cb_) { \
        sv_ = *(const uint4*)((const char*)stu_p  + ((u32)(I_).x + lane_off)); \
        iv_ = *(const uint4*)((const char*)item_p + ((u32)(I_).y + lane_off)); \
        const char* cp_ = (const char*)conc_cat + ((u32)(I_).z + lane_off); \
        ca_ = *(const uint4*)cp_; cb_ = *(const uint4*)(cp_ + 256); }

    // prefetch: issue NEXT stage's gathers + idx two ahead, fence, compute CURRENT
#define STEP(DA, DB, IA, IB, IC) { \
        GATH(I##IB, sv##DB, iv##DB, ca##DB, cb##DB); \
        I##IC = ldidx(q + 2 * S); \
        __builtin_amdgcn_sched_barrier(0); \
        compute(sv##DA, iv##DA, ca##DA, cb##DA, I##IA, q); \
        q += S; \
        if (q >= nQuads) break; }

    // preamble
    int4 I0 = ldidx(q), I1 = ldidx(q + S), I2, I3;
    uint4 sv0, iv0, ca0, cb0, sv1, iv1, ca1, cb1;
    GATH(I0, sv0, iv0, ca0, cb0);

    for (;;) {
        STEP(0, 1, 0, 1, 2)   // compute D0/I0, gather I1->D1, load I2
        STEP(1, 0, 1, 2, 3)   // compute D1/I1, gather I2->D0, load I3
        STEP(0, 1, 2, 3, 0)   // compute D0/I2, gather I3->D1, load I0
        STEP(1, 0, 3, 0, 1)   // compute D1/I3, gather I0->D0, load I1
    }
#undef STEP
#undef GATH
}

__global__ __launch_bounds__(256) void final_kernel(
    const double* __restrict__ sc,
    const float* __restrict__ b_pred, float* __restrict__ out, int M)
{
    const int i = blockIdx.x * blockDim.x + threadIdx.x;
    if (i < M) {
        const double acc = sc[i];
        const double cnt = rint(acc * (1.0 / CNT_SCALE));   // |sum| << 2^23
        const double sum = acc - cnt * CNT_SCALE;
        const float mean = (float)(sum / fmax(cnt, 1.0));
        out[i] = sig_std(mean + b_pred[0]);
    }
}

extern "C" void kernel_launch(void* const* d_in, const int* in_sizes, int n_in,
                              void* d_out, int out_size, void* d_ws, size_t ws_size,
                              hipStream_t stream) {
    const float* stu_x    = (const float*)d_in[0];
    const float* item_x   = (const float*)d_in[1];
    const float* conc_x   = (const float*)d_in[2];
    const float* W_stu    = (const float*)d_in[3];
    const float* b_stu    = (const float*)d_in[4];
    const float* W_item   = (const float*)d_in[5];
    const float* b_item   = (const float*)d_in[6];
    const float* W_pred   = (const float*)d_in[7];
    const float* b_pred   = (const float*)d_in[8];
    const int* stu_track  = (const int*)d_in[9];
    const int* item_index = (const int*)d_in[10];
    const int* conc_index = (const int*)d_in[11];
    const int* mean_index = (const int*)d_in[12];

    const int NS = in_sizes[0] / CDIM;
    const int NI = in_sizes[1] / CDIM;
    const int NC = in_sizes[2] / CDIM;
    const int E  = in_sizes[9];
    const int M  = out_size;

    // workspace layout (all pieces 16B-aligned)
    double* sc     = (double*)d_ws;              // [M] packed (sum + cnt*2^24)
    u16* Wstu_bf   = (u16*)(sc + M);             // Wstu_bf || Witem_bf contiguous
    u16* Witem_bf  = Wstu_bf + CDIM * CDIM;
    u16* stu_p     = Witem_bf + CDIM * CDIM;
    u16* item_p    = stu_p  + (size_t)NS * CDIM;
    u16* conc_cat  = item_p + (size_t)NI * CDIM; // [NC][256]: exp2 stu | item side
    int4* idx4     = (int4*)(conc_cat + (size_t)NC * 256);

    const int nZero4 = (int)(((size_t)M * sizeof(double)) / 16);
    prep_kernel<<<1024, 256, 0, stream>>>(W_stu, W_item, (u32*)Wstu_bf,
                                          (float4*)sc, nZero4,
                                          stu_track, item_index, conc_index,
                                          mean_index, idx4, E);

    const int T0 = (NS + 15) / 16, T1 = (NI + 15) / 16, T2 = (NC + 15) / 16;
    const int totalWaves = T0 + T1 + 2 * T2;
    proj4_kernel<<<(totalWaves + 3) / 4, 256, 0, stream>>>(
        stu_x, item_x, conc_x, Wstu_bf, Witem_bf, b_stu, b_item,
        stu_p, item_p, conc_cat, NS, NI, NC);

    edge_kernel<<<4096, 256, 0, stream>>>(stu_p, item_p, conc_cat,
                                          idx4, W_pred, sc, E);

    final_kernel<<<(M + 255) / 256, 256, 0, stream>>>(sc, b_pred, (float*)d_out, M);
}

// Round 7
// 195.988 us; speedup vs baseline: 1.1018x; 1.0265x over previous
//
#include <hip/hip_runtime.h>

typedef unsigned short u16;
typedef unsigned int   u32;

typedef short short8 __attribute__((ext_vector_type(8)));
typedef float floatx4 __attribute__((ext_vector_type(4)));

#define CDIM 128
#define K_NEG_LOG2E -1.4426950408889634f
#define CNT_SCALE 16777216.0   // 2^24: packs (sum, count) into one f64

// LDS weight tile: 128 rows x 136 u16 (272 B stride = 17*16 B).
// ds_read_b128 lanes m=0..15 then hit banks (m*68)%32 = 4m%32 -> 2-way
// aliasing only (free, vs 16-way at a 256 B stride).
#define WLDS_STRIDE 136
#define PACK_BLOCKS 512

__device__ __forceinline__ float bf2f_lo(u32 h) {
    union { u32 u; float f; } v; v.u = h << 16; return v.f;
}
__device__ __forceinline__ float bf2f_hi(u32 h) {
    union { u32 u; float f; } v; v.u = h & 0xffff0000u; return v.f;
}
__device__ __forceinline__ u16 f2bf(float f) {
    union { float f; u32 u; } v; v.f = f;
    u32 u = v.u;
    return (u16)((u + 0x7FFFu + ((u >> 16) & 1u)) >> 16);  // RNE
}
__device__ __forceinline__ float sig_std(float x) {
    return __builtin_amdgcn_rcpf(1.0f + __builtin_amdgcn_exp2f(x * K_NEG_LOG2E));
}

// One wave computes a 16-row tile from the LDS weight tile; stores
// exp2(proj + bias) in bf16.
__device__ __forceinline__ void proj_tile16_lds(
    const float* __restrict__ X, const u16* __restrict__ wlds,
    const float* __restrict__ bias, u16* __restrict__ out,
    int nrows, int ostride, int ooff, int row0, int lane)
{
    const int m = lane & 15;   // A-row / B-col / D-col
    const int g = lane >> 4;   // k-quad

    short8 a[4];
    {
        int arow = row0 + m;
        if (arow >= nrows) arow = nrows - 1;   // clamp; stores masked below
        const float* xrow = X + (size_t)arow * CDIM;
#pragma unroll
        for (int s = 0; s < 4; ++s) {
            float4 f0 = *(const float4*)(xrow + s * 32 + g * 8);
            float4 f1 = *(const float4*)(xrow + s * 32 + g * 8 + 4);
            a[s][0] = (short)f2bf(f0.x); a[s][1] = (short)f2bf(f0.y);
            a[s][2] = (short)f2bf(f0.z); a[s][3] = (short)f2bf(f0.w);
            a[s][4] = (short)f2bf(f1.x); a[s][5] = (short)f2bf(f1.y);
            a[s][6] = (short)f2bf(f1.z); a[s][7] = (short)f2bf(f1.w);
        }
    }

#pragma unroll
    for (int ct = 0; ct < 8; ++ct) {
        const u16* wrow = wlds + (size_t)(ct * 16 + m) * WLDS_STRIDE;
        floatx4 acc = {0.f, 0.f, 0.f, 0.f};
#pragma unroll
        for (int s = 0; s < 4; ++s) {
            short8 b = *(const short8*)(wrow + s * 32 + g * 8);
            acc = __builtin_amdgcn_mfma_f32_16x16x32_bf16(a[s], b, acc, 0, 0, 0);
        }
        const int col = ct * 16 + m;           // D: col = lane&15
        const float badd = bias ? bias[col] * K_NEG_LOG2E : 0.f;
#pragma unroll
        for (int i = 0; i < 4; ++i) {
            int r = row0 + g * 4 + i;          // D: row = (lane>>4)*4 + reg
            if (r < nrows)
                out[(size_t)r * ostride + ooff + col] =
                    f2bf(__builtin_amdgcn_exp2f(acc[i] + badd));
        }
    }
}

// ONE launch replacing prep+proj4. Block roles:
//   [0, PBtot): projection blocks. Each owns 64 rows of one segment,
//     converts its f32 W into a pre-scaled bf16 LDS tile (amortized over
//     4 waves), then runs 4x proj_tile16_lds. No cross-block W dependency.
//   [PBtot, PBtot+PACK_BLOCKS): zero the f64 accumulators and pack the
//     four edge-index arrays into int4 byte-offsets — fully overlapped
//     with projection instead of serialized before it.
__global__ __launch_bounds__(256) void fused_prep_proj(
    const float* __restrict__ stu_x, const float* __restrict__ item_x,
    const float* __restrict__ conc_x,
    const float* __restrict__ Wstu, const float* __restrict__ Witem,
    const float* __restrict__ b_stu, const float* __restrict__ b_item,
    u16* __restrict__ stu_p, u16* __restrict__ item_p, u16* __restrict__ conc_cat,
    float4* __restrict__ zero4, int nZero4,
    const int* __restrict__ stu_track, const int* __restrict__ item_index,
    const int* __restrict__ conc_index, const int* __restrict__ mean_index,
    int4* __restrict__ idx4, int E,
    int NS, int NI, int NC)
{
    __shared__ u16 wlds[128 * WLDS_STRIDE];

    const int PB0 = (NS + 63) / 64, PB1 = (NI + 63) / 64, PB2 = (NC + 63) / 64;
    const int PBtot = PB0 + PB1 + 2 * PB2;
    int b = blockIdx.x;

    if (b >= PBtot) {
        // ---- pack/zero role ----
        const int tid = (b - PBtot) * 256 + threadIdx.x;
        const int stride = PACK_BLOCKS * 256;
        const float4 z = {0.f, 0.f, 0.f, 0.f};
        for (int i = tid; i < nZero4; i += stride) zero4[i] = z;
        for (int e = tid; e < E; e += stride) {
            int4 t;
            t.x = stu_track[e]  << 8;   // 256 B rows
            t.y = item_index[e] << 8;   // 256 B rows
            t.z = conc_index[e] << 9;   // 512 B rows (cat)
            t.w = mean_index[e] << 3;   // f64 slots
            idx4[e] = t;
        }
        return;
    }

    // ---- projection role: segment select (block-uniform) ----
    const float* X; const float* Wsel; const float* bias;
    u16* out; int nrows, ostride, ooff, base;
    if (b < PB0)      { X = stu_x;  Wsel = Wstu;  bias = nullptr; out = stu_p;
                        nrows = NS; ostride = 128; ooff = 0;   base = b * 64; }
    else if ((b -= PB0) < PB1)
                      { X = item_x; Wsel = Witem; bias = nullptr; out = item_p;
                        nrows = NI; ostride = 128; ooff = 0;   base = b * 64; }
    else if ((b -= PB1) < PB2)
                      { X = conc_x; Wsel = Wstu;  bias = b_stu;  out = conc_cat;
                        nrows = NC; ostride = 256; ooff = 0;   base = b * 64; }
    else              { b -= PB2;
                        X = conc_x; Wsel = Witem; bias = b_item; out = conc_cat;
                        nrows = NC; ostride = 256; ooff = 128; base = b * 64; }

    // convert this block's W (f32 -> pre-scaled bf16) into LDS
    {
        const int t   = threadIdx.x;
        const int col = t >> 1;
        const int k0  = (t & 1) * 64;
        const float4* src = (const float4*)(Wsel + col * 128 + k0);
        u32* dst = (u32*)(wlds + col * WLDS_STRIDE + k0);
#pragma unroll
        for (int i = 0; i < 16; ++i) {
            float4 f = src[i];
            dst[2 * i]     = (u32)f2bf(f.x * K_NEG_LOG2E) |
                             ((u32)f2bf(f.y * K_NEG_LOG2E) << 16);
            dst[2 * i + 1] = (u32)f2bf(f.z * K_NEG_LOG2E) |
                             ((u32)f2bf(f.w * K_NEG_LOG2E) << 16);
        }
    }
    __syncthreads();

    const int lane = threadIdx.x & 63;
    const int row0 = base + (threadIdx.x >> 6) * 16;
    if (row0 < nrows)
        proj_tile16_lds(X, wlds, bias, out, nrows, ostride, ooff, row0, lane);
}

// 16 lanes per edge, 4 edges per wave. Tables hold E = 2^(pre-scaled proj).
// Proven 72 us structure (depth-1 data / depth-2 idx ping-pong, 4096
// blocks, shfl_xor reduction) — reverted after R0/R3/R4 experiments all
// came back null-or-negative on edge.
__global__ __launch_bounds__(256) void edge_kernel(
    const u16* __restrict__ stu_p, const u16* __restrict__ item_p,
    const u16* __restrict__ conc_cat,
    const int4* __restrict__ idx4,     // byte offsets {stu, item, conc, mean}
    const float* __restrict__ w_pred,
    double* __restrict__ sc, int E)
{
    const int lane = threadIdx.x & 63;
    const int sub  = lane & 15;      // position within edge
    const int g    = lane >> 4;      // edge within quad
    const int waveId = (int)((blockIdx.x * blockDim.x + threadIdx.x) >> 6);
    const int S      = (int)((gridDim.x * blockDim.x) >> 6);   // wave stride

    const float4 wA = ((const float4*)w_pred)[sub * 2];
    const float4 wB = ((const float4*)w_pred)[sub * 2 + 1];
    float2 w2[4];
    w2[0] = make_float2(wA.x, wA.y); w2[1] = make_float2(wA.z, wA.w);
    w2[2] = make_float2(wB.x, wB.y); w2[3] = make_float2(wB.z, wB.w);
    const u32 lane_off = (u32)sub * 16;

    const int nQuads = (E + 3) >> 2;
    int q = waveId;
    if (q >= nQuads) return;

    // always-safe index load: edge id clamped to E-1
    auto ldidx = [&](int qq) -> int4 {
        int e = qq * 4 + g;
        e = (e < E) ? e : (E - 1);
        return idx4[e];
    };
    auto compute = [&](const uint4& sv, const uint4& iv,
                       const uint4& ca, const uint4& cb,
                       const int4& I, int qq) {
        const u32 su[4] = {sv.x, sv.y, sv.z, sv.w};
        const u32 iu[4] = {iv.x, iv.y, iv.z, iv.w};
        const u32 au[4] = {ca.x, ca.y, ca.z, ca.w};
        const u32 bu[4] = {cb.x, cb.y, cb.z, cb.w};
        const float2 one = make_float2(1.f, 1.f);
        float2 vacc = make_float2(0.f, 0.f);
#pragma unroll
        for (int j = 0; j < 4; ++j) {
            float2 A  = make_float2(bf2f_lo(au[j]), bf2f_hi(au[j]));
            float2 Sx = make_float2(bf2f_lo(su[j]), bf2f_hi(su[j]));
            float2 B  = make_float2(bf2f_lo(bu[j]), bf2f_hi(bu[j]));
            float2 Ix = make_float2(bf2f_lo(iu[j]), bf2f_hi(iu[j]));
            float2 ea = A * Sx;                    // v_pk_mul_f32
            float2 eb = B * Ix;
            float2 den = (ea + one) * (eb + one);  // (1+ea)(1+eb)
            float2 num = eb - ea;
            float2 rd = make_float2(__builtin_amdgcn_rcpf(den.x),
                                    __builtin_amdgcn_rcpf(den.y));
            vacc += (num * rd) * w2[j];
        }
        float v = vacc.x + vacc.y;
        v += __shfl_xor(v, 1, 64);
        v += __shfl_xor(v, 2, 64);
        v += __shfl_xor(v, 4, 64);
        v += __shfl_xor(v, 8, 64);
        if (sub == 0 && (qq * 4 + g) < E)
            atomicAdd((double*)((char*)sc + (u32)I.w), (double)v + CNT_SCALE);
    };

#define GATH(I_, sv_, iv_, ca_, cb_) { \
        sv_ = *(const uint4*)((const char*)stu_p  + ((u32)(I_).x + lane_off)); \
        iv_ = *(const uint4*)((const char*)item_p + ((u32)(I_).y + lane_off)); \
        const char* cp_ = (const char*)conc_cat + ((u32)(I_).z + lane_off); \
        ca_ = *(const uint4*)cp_; cb_ = *(const uint4*)(cp_ + 256); }

    // prefetch: issue NEXT stage's gathers + idx two ahead, fence, compute CURRENT
#define STEP(DA, DB, IA, IB, IC) { \
        GATH(I##IB, sv##DB, iv##DB, ca##DB, cb##DB); \
        I##IC = ldidx(q + 2 * S); \
        __builtin_amdgcn_sched_barrier(0); \
        compute(sv##DA, iv##DA, ca##DA, cb##DA, I##IA, q); \
        q += S; \
        if (q >= nQuads) break; }

    // preamble
    int4 I0 = ldidx(q), I1 = ldidx(q + S), I2, I3;
    uint4 sv0, iv0, ca0, cb0, sv1, iv1, ca1, cb1;
    GATH(I0, sv0, iv0, ca0, cb0);

    for (;;) {
        STEP(0, 1, 0, 1, 2)   // compute D0/I0, gather I1->D1, load I2
        STEP(1, 0, 1, 2, 3)   // compute D1/I1, gather I2->D0, load I3
        STEP(0, 1, 2, 3, 0)   // compute D0/I2, gather I3->D1, load I0
        STEP(1, 0, 3, 0, 1)   // compute D1/I3, gather I0->D0, load I1
    }
#undef STEP
#undef GATH
}

__global__ __launch_bounds__(256) void final_kernel(
    const double* __restrict__ sc,
    const float* __restrict__ b_pred, float* __restrict__ out, int M)
{
    const int i = blockIdx.x * blockDim.x + threadIdx.x;
    if (i < M) {
        const double acc = sc[i];
        const double cnt = rint(acc * (1.0 / CNT_SCALE));   // |sum| << 2^23
        const double sum = acc - cnt * CNT_SCALE;
        const float mean = (float)(sum / fmax(cnt, 1.0));
        out[i] = sig_std(mean + b_pred[0]);
    }
}

extern "C" void kernel_launch(void* const* d_in, const int* in_sizes, int n_in,
                              void* d_out, int out_size, void* d_ws, size_t ws_size,
                              hipStream_t stream) {
    const float* stu_x    = (const float*)d_in[0];
    const float* item_x   = (const float*)d_in[1];
    const float* conc_x   = (const float*)d_in[2];
    const float* W_stu    = (const float*)d_in[3];
    const float* b_stu    = (const float*)d_in[4];
    const float* W_item   = (const float*)d_in[5];
    const float* b_item   = (const float*)d_in[6];
    const float* W_pred   = (const float*)d_in[7];
    const float* b_pred   = (const float*)d_in[8];
    const int* stu_track  = (const int*)d_in[9];
    const int* item_index = (const int*)d_in[10];
    const int* conc_index = (const int*)d_in[11];
    const int* mean_index = (const int*)d_in[12];

    const int NS = in_sizes[0] / CDIM;
    const int NI = in_sizes[1] / CDIM;
    const int NC = in_sizes[2] / CDIM;
    const int E  = in_sizes[9];
    const int M  = out_size;

    // workspace layout (all pieces 16B-aligned)
    double* sc     = (double*)d_ws;              // [M] packed (sum + cnt*2^24)
    u16* stu_p     = (u16*)(sc + M);
    u16* item_p    = stu_p  + (size_t)NS * CDIM;
    u16* conc_cat  = item_p + (size_t)NI * CDIM; // [NC][256]: exp2 stu | item side
    int4* idx4     = (int4*)(conc_cat + (size_t)NC * 256);

    const int nZero4 = (int)(((size_t)M * sizeof(double)) / 16);
    const int PB0 = (NS + 63) / 64, PB1 = (NI + 63) / 64, PB2 = (NC + 63) / 64;
    const int PBtot = PB0 + PB1 + 2 * PB2;

    fused_prep_proj<<<PBtot + PACK_BLOCKS, 256, 0, stream>>>(
        stu_x, item_x, conc_x, W_stu, W_item, b_stu, b_item,
        stu_p, item_p, conc_cat,
        (float4*)sc, nZero4,
        stu_track, item_index, conc_index, mean_index, idx4, E,
        NS, NI, NC);

    edge_kernel<<<4096, 256, 0, stream>>>(stu_p, item_p, conc_cat,
                                          idx4, W_pred, sc, E);

    final_kernel<<<(M + 255) / 256, 256, 0, stream>>>(sc, b_pred, (float*)d_out, M);
}